// Round 9
// baseline (162.630 us; speedup 1.0000x reference)
//
#include <hip/hip_runtime.h>
#include <hip/hip_bf16.h>

// GQA forward. fp32 in/out. Flash-style, 16x16x32 bf16 MFMA, fp32 accum.
// R17 = R16 + unit-level software pipeline (register-neutral).
// R16 evidence: MfmaUtil 43.6 + VALUBusy 42.9 ~= 87% and dur ~= their SUM ->
// pipes mutually exclusive in time. Cause is intra-wave: exp() reads the QK
// accumulators right after issuing the MFMAs -> wave stalls till matrix pipe
// drains, then matrix pipe idles through exp/cvtpk. MFMA is async until the
// acc is read — exploit it:
//   iter kt: stage(kt+1); QK(kt,0)->accA; finish(kt-1,1:accB);
//            QK(kt,1)->accB; finish(kt,0:accA); barrier
// Each finish (exp+cvtpk+PV of the PREVIOUS unit) executes on VALU while the
// just-issued QK cluster drains in the matrix pipe; PV MFMAs queue behind.
//  - accA/accB = 32 regs = same budget as R16's accT[2][4] -> VGPR/occupancy
//    preserved (unlike quarantined R13-15).
//  - V of tile kt-1 must outlive the staging of kt+1 -> LDS = K dbuf (2x8KB)
//    + V TRIPLE buffer (3x8KB) = 40KB; 4 blocks/CU = 160KB exactly.
//  - ws layout unchanged (K half [0,4096), V half [4096,8192) shorts);
//    prepack kernel byte-identical to R16. Staging = 2+2 DMA, wave-uniform
//    dst (verified pattern). Per-unit math byte-identical to R16.
// R16: 75.6us main, VALUBusy 42.9, MfmaUtil 43.6, conflicts 0, occ 30%.

#define S_LEN 2048
#define E_DIM 2048
#define KV_E  512
#define D_HEAD 64
#define BN 64
#define NTILE (S_LEN / BN)   // 32 k/v tiles

typedef __attribute__((ext_vector_type(8))) short short8;   // 8 bf16 (A/B frag)
typedef __attribute__((ext_vector_type(4))) float floatx4;  // C/D frag
typedef __attribute__((ext_vector_type(4))) unsigned int uint4v;

__device__ __forceinline__ short bf(float x) {
    return __builtin_bit_cast(short, __float2bfloat16(x));
}
__device__ __forceinline__ unsigned cvtpk(float lo, float hi) {
    unsigned r;
    asm("v_cvt_pk_bf16_f32 %0, %1, %2" : "=v"(r) : "v"(lo), "v"(hi));
    return r;
}
__device__ __forceinline__ float vexp2(float x) {
    float r;
    asm("v_exp_f32 %0, %1" : "=v"(r) : "v"(x));
    return r;
}

// ---------------- pre-pass: K/V -> fragment-major bf16 tiles ----------------
// ws tile t = ((b*8 + kvh)*32 + kt): 16 fragments x 1KB (8192 shorts).
//   frag fk = ks*4 + t      (fk<8):  lane l=(quad,lc) holds
//       K[rowK(t,lc)][ks*32+quad*8 .. +7],
//       rowK = 8*(lc>>2)+(lc&3)+4*(t&1)+32*(t>>1)   (permuted K-row feed)
//   frag fk = 8 + ks*4 + nt (fk>=8): lane l holds
//       V[ks*32+quad*8+j][nt*16+lc], j=0..7        (V^T fragment)
__global__ __launch_bounds__(256)
void gqa_prepack_kernel(const float* __restrict__ k, const float* __restrict__ v,
                        short* __restrict__ ws) {
    __shared__ float kf[BN][D_HEAD + 2];
    __shared__ float vf[BN][D_HEAD + 2];
    const int kt = blockIdx.x, kvh = blockIdx.y, b = blockIdx.z;
    const int tid = threadIdx.x;
    short* wt = ws + ((size_t)(b * 8 + kvh) * NTILE + kt) * 8192;
    const float* kb = k + ((size_t)(b * S_LEN + kt * BN)) * KV_E + kvh * D_HEAD;
    const float* vb = v + ((size_t)(b * S_LEN + kt * BN)) * KV_E + kvh * D_HEAD;

    #pragma unroll
    for (int i = tid; i < 1024; i += 256) {
        const int r = i >> 4, c0 = (i & 15) << 2;
        floatx4 k4 = *((const floatx4*)(kb + (size_t)r * KV_E + c0));
        floatx4 v4 = *((const floatx4*)(vb + (size_t)r * KV_E + c0));
        kf[r][c0] = k4[0]; kf[r][c0 + 1] = k4[1]; kf[r][c0 + 2] = k4[2]; kf[r][c0 + 3] = k4[3];
        vf[r][c0] = v4[0]; vf[r][c0 + 1] = v4[1]; vf[r][c0 + 2] = v4[2]; vf[r][c0 + 3] = v4[3];
    }
    __syncthreads();
    #pragma unroll
    for (int c = tid; c < 1024; c += 256) {
        const int fk = c >> 6, l = c & 63;
        const int quad = l >> 4, lc = l & 15;
        const int ks = (fk >> 2) & 1, sub = fk & 3;
        short8 s;
        if (fk < 8) {   // K fragment, permuted row
            const int row = ((lc >> 2) << 3) + (lc & 3) + ((sub & 1) << 2) + ((sub >> 1) << 5);
            const int c0 = ks * 32 + quad * 8;
            #pragma unroll
            for (int j = 0; j < 8; ++j) s[j] = bf(kf[row][c0 + j]);
        } else {        // V^T fragment
            const int d = sub * 16 + lc;
            const int k0 = ks * 32 + quad * 8;
            #pragma unroll
            for (int j = 0; j < 8; ++j) s[j] = bf(vf[k0 + j][d]);
        }
        *((short8*)(wt + c * 8)) = s;   // coalesced 16B/thread
    }
}

// ---------------- main kernel ----------------
__global__ __launch_bounds__(256, 4)
void GroupedQueryAttention_36163624632989_kernel(
        const float* __restrict__ q,
        const short* __restrict__ ws,
        float* __restrict__ out, const int B) {
    // K double-buffer (2x4096 shorts) + V triple-buffer (3x4096 shorts) = 40KB
    __shared__ short lds[2 * 4096 + 3 * 4096];
    short* ldsK = lds;
    short* ldsV = lds + 2 * 4096;

    // XCD-aware swizzle of a 1-D grid (gridDim.x = B*512, %8==0):
    // XCD x gets exactly the blocks of kvh==x (whole bf16 K/V stream in L2).
    const int f = blockIdx.x;
    const int chunk = gridDim.x >> 3;
    const int wg = (f & 7) * chunk + (f >> 3);
    const int qt = wg & 31;
    const int t2 = wg >> 5;
    const int b  = t2 % B;
    const int hp = t2 / B;                 // head pair 0..15
    const int kvh = hp >> 1;

    const int tid  = threadIdx.x;
    const int w    = tid >> 6;             // wave 0..3
    const int lane = tid & 63;
    const int quad = lane >> 4;
    const int lc   = lane & 15;

    const int h = (hp << 1) + (w & 1);     // q head
    const int rowhalf = w >> 1;            // 32-row half of the 64-row q tile

    const float SCL = 1.4426950408889634f / 8.0f;  // log2(e)/sqrt(D) folded into Q

    // all-ones bf16 B-fragment for the MFMA row-sum (bf16 1.0 = 0x3F80)
    const short ONE = (short)0x3F80;
    const short8 ones8 = {ONE, ONE, ONE, ONE, ONE, ONE, ONE, ONE};

    // ---- Q fragments (B-operand of swapped QK^T: n = lc, k = quad*8+j) ----
    short8 aq[2][2];                       // [mt][ks]
    #pragma unroll
    for (int mt = 0; mt < 2; ++mt) {
        const int qrow = qt * 64 + rowhalf * 32 + mt * 16 + lc;
        const float* qp = q + ((size_t)(b * S_LEN + qrow)) * E_DIM + h * D_HEAD;
        #pragma unroll
        for (int ks = 0; ks < 2; ++ks) {
            const float* p = qp + ks * 32 + quad * 8;
            floatx4 qa = *((const floatx4*)p);
            floatx4 qb = *((const floatx4*)(p + 4));
            aq[mt][ks][0] = bf(qa[0] * SCL); aq[mt][ks][1] = bf(qa[1] * SCL);
            aq[mt][ks][2] = bf(qa[2] * SCL); aq[mt][ks][3] = bf(qa[3] * SCL);
            aq[mt][ks][4] = bf(qb[0] * SCL); aq[mt][ks][5] = bf(qb[1] * SCL);
            aq[mt][ks][6] = bf(qb[2] * SCL); aq[mt][ks][7] = bf(qb[3] * SCL);
        }
    }

    floatx4 o_acc[2][4];                   // [mt][nt]: O[qrow=mt*16+quad*4+r][d=nt*16+lc]
    floatx4 accL[2];                       // [mt]: l(qrow=mt*16+quad*4+r), same C-layout
    #pragma unroll
    for (int mt = 0; mt < 2; ++mt) {
        accL[mt] = (floatx4){0.f, 0.f, 0.f, 0.f};
        #pragma unroll
        for (int i = 0; i < 4; ++i)
            o_acc[mt][i] = (floatx4){0.f, 0.f, 0.f, 0.f};
    }

    const short* wsT = ws + (size_t)(b * 8 + kvh) * NTILE * 8192;

    // async stage: per wave 2KB of K + 2KB of V, wave-uniform LDS dsts
    // (w*1024 shorts); HW adds lane*16B. Per-lane addr only on global src.
    auto stageKV = [&](int kbuf, int vbuf, int kt) {
        const short* srcK = wsT + (size_t)kt * 8192 + w * 1024 + (lane << 3);
        short* dstK = ldsK + kbuf * 4096 + w * 1024;
        #pragma unroll
        for (int i = 0; i < 2; ++i)
            __builtin_amdgcn_global_load_lds(
                (const __attribute__((address_space(1))) void*)(srcK + i * 512),
                (__attribute__((address_space(3))) void*)(dstK + i * 512),
                16, 0, 0);
        const short* srcV = wsT + (size_t)kt * 8192 + 4096 + w * 1024 + (lane << 3);
        short* dstV = ldsV + vbuf * 4096 + w * 1024;
        #pragma unroll
        for (int i = 0; i < 2; ++i)
            __builtin_amdgcn_global_load_lds(
                (const __attribute__((address_space(1))) void*)(srcV + i * 512),
                (__attribute__((address_space(3))) void*)(dstV + i * 512),
                16, 0, 0);
    };

    // QK of one m-tile: 8 MFMA into acc (S^T layout == PV A-frag layout)
    auto qk_mt = [&](const short* fbK, const short8 (&aqm)[2], floatx4 (&acc)[4]) {
        #pragma unroll
        for (int t = 0; t < 4; ++t) acc[t] = (floatx4){0.f, 0.f, 0.f, 0.f};
        #pragma unroll
        for (int ks = 0; ks < 2; ++ks) {
            __builtin_amdgcn_s_setprio(1);
            #pragma unroll
            for (int t = 0; t < 4; ++t) {
                short8 bk = *((const short8*)(fbK + (ks * 4 + t) * 512));
                acc[t] = __builtin_amdgcn_mfma_f32_16x16x32_bf16(
                    bk, aqm[ks], acc[t], 0, 0, 0);
            }
            __builtin_amdgcn_s_setprio(0);
        }
    };

    // finish of one unit: exp+cvtpk (VALU) + PV & ones (MFMA), math == R16
    auto finish = [&](const floatx4 (&sT)[4], const short* fbV,
                      floatx4 (&oac)[4], floatx4& aL) {
        #pragma unroll
        for (int ks = 0; ks < 2; ++ks) {
            short8 bv4[4];
            #pragma unroll
            for (int nt = 0; nt < 4; ++nt)
                bv4[nt] = *((const short8*)(fbV + (ks * 4 + nt) * 512));
            float e0[4], e1[4];
            #pragma unroll
            for (int r = 0; r < 4; ++r) {
                e0[r] = vexp2(sT[2 * ks][r]);      // kpos = ks*32+8q+r
                e1[r] = vexp2(sT[2 * ks + 1][r]);  // kpos = ks*32+8q+4+r
            }
            const unsigned a0 = cvtpk(e0[0], e0[1]);
            const unsigned a1 = cvtpk(e0[2], e0[3]);
            const unsigned a2 = cvtpk(e1[0], e1[1]);
            const unsigned a3 = cvtpk(e1[2], e1[3]);
            const short8 ap = __builtin_bit_cast(short8, (uint4v){a0, a1, a2, a3});
            __builtin_amdgcn_s_setprio(1);
            #pragma unroll
            for (int nt = 0; nt < 4; ++nt)
                oac[nt] = __builtin_amdgcn_mfma_f32_16x16x32_bf16(
                    ap, bv4[nt], oac[nt], 0, 0, 0);
            aL = __builtin_amdgcn_mfma_f32_16x16x32_bf16(ap, ones8, aL, 0, 0, 0);
            __builtin_amdgcn_s_setprio(0);
        }
    };

    floatx4 accA[4], accB[4];              // S^T double-buffer (32 regs total)

    // ---- prologue: tile 0 staged; peel kt=0 ----
    stageKV(0, 0, 0);
    __syncthreads();                       // tile 0 ready
    stageKV(1, 1, 1);                      // prefetch tile 1 (disjoint bufs)
    {
        const short* fbK = ldsK + (lane << 3);
        const short* fbV = ldsV + (lane << 3);
        qk_mt(fbK, aq[0], accA);           // unit (0,0)
        qk_mt(fbK, aq[1], accB);           // unit (0,1)
        finish(accA, fbV, o_acc[0], accL[0]);   // finish (0,0); (0,1) deferred
    }
    __syncthreads();                       // tile 1 ready; all waves done w/ bufs
    int vprev = 0, vcur = 1;

    // ---- steady state ----
    for (int kt = 1; kt < NTILE; ++kt) {
        const int vnext = (vcur == 2) ? 0 : vcur + 1;   // (kt+1)%3
        if (kt + 1 < NTILE) stageKV((kt + 1) & 1, vnext, kt + 1);

        const short* fbK  = ldsK + (kt & 1) * 4096 + (lane << 3);
        const short* fbVp = ldsV + vprev * 4096 + (lane << 3);  // V(kt-1)
        const short* fbVc = ldsV + vcur * 4096 + (lane << 3);   // V(kt)

        qk_mt(fbK, aq[0], accA);                     // QK (kt,0) -> queue
        finish(accB, fbVp, o_acc[1], accL[1]);       // finish (kt-1,1) overlaps
        qk_mt(fbK, aq[1], accB);                     // QK (kt,1) -> queue
        finish(accA, fbVc, o_acc[0], accL[0]);       // finish (kt,0) overlaps

        __syncthreads();   // readers done with rotated-out bufs; DMA drained
        vprev = vcur; vcur = vnext;
    }
    // tail: finish (31,1); V(31) sits in vbuf vprev, never overwritten
    finish(accB, ldsV + vprev * 4096 + (lane << 3), o_acc[1], accL[1]);

    // ---- epilogue: accL rows align with o_acc rows -> pure per-lane divide ----
    #pragma unroll
    for (int mt = 0; mt < 2; ++mt) {
        float* op = out + (size_t)b * S_LEN * E_DIM + h * D_HEAD;
        #pragma unroll
        for (int r = 0; r < 4; ++r) {
            const float inv_l = 1.0f / accL[mt][r];   // l(qrow=mt*16+quad*4+r)
            const int grow = qt * 64 + rowhalf * 32 + mt * 16 + quad * 4 + r;
            #pragma unroll
            for (int nt = 0; nt < 4; ++nt)
                op[(size_t)grow * E_DIM + nt * 16 + lc] = o_acc[mt][nt][r] * inv_l;
        }
    }
}

extern "C" void kernel_launch(void* const* d_in, const int* in_sizes, int n_in,
                              void* d_out, int out_size, void* d_ws, size_t ws_size,
                              hipStream_t stream) {
    const float* q = (const float*)d_in[0];
    const float* k = (const float*)d_in[1];
    const float* v = (const float*)d_in[2];
    float* out = (float*)d_out;
    short* ws = (short*)d_ws;              // needs B*4MB (8MB at B=2)
    const int B = in_sizes[0] / (S_LEN * E_DIM);

    dim3 pgrid(NTILE, 8, B);
    gqa_prepack_kernel<<<pgrid, 256, 0, stream>>>(k, v, ws);

    dim3 grid(B * 512);                    // 1-D, decoded + XCD-swizzled in-kernel
    GroupedQueryAttention_36163624632989_kernel<<<grid, 256, 0, stream>>>(q, ws, out, B);
}